// Round 6
// baseline (1507.844 us; speedup 1.0000x reference)
//
#include <hip/hip_runtime.h>
#include <math.h>

#define N_NODES 50000
#define M_ENS   20
#define C_IN    32
#define H       128
#define E_EDGES 800000
#define L_LAYERS 3
#define BN_EPS  1e-5f

// ---------------------------------------------------------------------------
// k_fold: precompute folded weights (once per launch):
//   g=0: Wf1 = phi_w2 @ rho_w1,            bf1 = 20*phi_b2 @ rho_w1 + rho_b1
//   g=1: Wf2 = rho_w2 @ dr_w[32:],         bf2 = rho_b2 @ dr_w[32:] + dr_b
// ---------------------------------------------------------------------------
__global__ __launch_bounds__(256) void k_fold(
    const float* __restrict__ w2,  const float* __restrict__ b2,
    const float* __restrict__ rw1, const float* __restrict__ rb1,
    const float* __restrict__ rw2, const float* __restrict__ rb2,
    const float* __restrict__ dr_w, const float* __restrict__ dr_b,
    float* __restrict__ Wf1, float* __restrict__ bf1,
    float* __restrict__ Wf2, float* __restrict__ bf2)
{
    const int g = blockIdx.x >> 7;
    const int j = blockIdx.x & 127;
    const int t = threadIdx.x;

    const float* A  = g ? rw2 : w2;
    const float* Bm = g ? (dr_w + C_IN * H) : rw1;

    __shared__ float s_col[H];
    if (t < H) s_col[t] = Bm[t * H + j];
    __syncthreads();

    const int r = t >> 1, q = t & 1;
    const float* arow = &A[r * H + q * 64];
    const float* cp = &s_col[q * 64];
    float acc = 0.f;
    #pragma unroll
    for (int u = 0; u < 64; u += 4) {
        const float4 av = *(const float4*)&arow[u];
        acc = fmaf(av.x, cp[u], acc);
        acc = fmaf(av.y, cp[u + 1], acc);
        acc = fmaf(av.z, cp[u + 2], acc);
        acc = fmaf(av.w, cp[u + 3], acc);
    }
    acc += __shfl_xor(acc, 1);
    if (q == 0) (g ? Wf2 : Wf1)[r * H + j] = acc;

    if (t == 0) {
        float bacc = g ? dr_b[j] : rb1[j];
        const float* bsrc = g ? rb2 : b2;
        const float scale = g ? 1.f : 20.f;
        for (int k = 0; k < H; ++k)
            bacc = fmaf(scale * bsrc[k], s_col[k], bacc);
        (g ? bf2 : bf1)[j] = bacc;
    }
}

// ---------------------------------------------------------------------------
// k_embed: per-node chain with folded weights.
// Stage 1 restructured: m-tiled (4 at a time), ensemble transposed in LDS to
// s_e[node][k][m] so the 4 m-values read as one broadcast float4; weights
// streamed as coalesced float2 rows (L1-resident) -> no per-thread weight
// array -> no register demotion (R5's VGPR=52 < 64 needed proved demotion).
// ---------------------------------------------------------------------------
#define ENB 8
__global__ __launch_bounds__(256) void k_embed(
    const float* __restrict__ ensemble, const float* __restrict__ x,
    const float* __restrict__ phi_w1,   const float* __restrict__ phi_b1,
    const float* __restrict__ Wf1, const float* __restrict__ bf1,
    const float* __restrict__ Wf2, const float* __restrict__ bf2,
    const float* __restrict__ dr_w,
    float* __restrict__ h_out)
{
    const int n0 = blockIdx.x * ENB;
    const int t  = threadIdx.x;
    const int jp = t & 63;  const int j0 = jp * 2;
    const int np = t >> 6;  const int na = np * 2, nb = na + 1;

    __shared__ __align__(16) float s_e[ENB][C_IN * M_ENS];  // [node][k*20+m], 20 KB
    __shared__ __align__(16) float s_h[ENB][H];
    __shared__ __align__(16) float s_t[ENB][H];
    __shared__ __align__(16) float s_x[ENB][C_IN];

    // stage ensemble transposed: global [n][m][k] -> LDS [n][k*20+m]
    for (int i = t; i < ENB * M_ENS * C_IN; i += 256) {
        const int q = i / (M_ENS * C_IN);
        const int rem = i - q * (M_ENS * C_IN);
        const int m = rem >> 5;          // rem / 32
        const int k = rem & 31;          // rem % 32
        s_e[q][k * M_ENS + m] =
            ensemble[(size_t)(n0 + q) * (M_ENS * C_IN) + rem];
    }
    s_x[t >> 5][t & 31] = x[(size_t)n0 * C_IN + t];
    __syncthreads();

    const float b1a = phi_b1[j0], b1b = phi_b1[j0 + 1];

    // ---- stage 1: hsum = sum_m relu(ens_m @ w1 + b1), m tiled by 4 ----
    float hs00 = 0.f, hs01 = 0.f, hs10 = 0.f, hs11 = 0.f;
    const float* ea = &s_e[na][0];
    const float* eb = &s_e[nb][0];
    for (int m0 = 0; m0 < M_ENS; m0 += 4) {
        float a0x[4], a0y[4], a1x[4], a1y[4];
        #pragma unroll
        for (int mm = 0; mm < 4; ++mm) {
            a0x[mm] = b1a; a0y[mm] = b1b;
            a1x[mm] = b1a; a1y[mm] = b1b;
        }
        const float* wp = &phi_w1[j0];
        #pragma unroll 4
        for (int k = 0; k < C_IN; ++k) {
            const float2 w  = *(const float2*)wp; wp += H;
            const float4 e0 = *(const float4*)&ea[k * M_ENS + m0];
            const float4 e1 = *(const float4*)&eb[k * M_ENS + m0];
            a0x[0] = fmaf(e0.x, w.x, a0x[0]); a0y[0] = fmaf(e0.x, w.y, a0y[0]);
            a1x[0] = fmaf(e1.x, w.x, a1x[0]); a1y[0] = fmaf(e1.x, w.y, a1y[0]);
            a0x[1] = fmaf(e0.y, w.x, a0x[1]); a0y[1] = fmaf(e0.y, w.y, a0y[1]);
            a1x[1] = fmaf(e1.y, w.x, a1x[1]); a1y[1] = fmaf(e1.y, w.y, a1y[1]);
            a0x[2] = fmaf(e0.z, w.x, a0x[2]); a0y[2] = fmaf(e0.z, w.y, a0y[2]);
            a1x[2] = fmaf(e1.z, w.x, a1x[2]); a1y[2] = fmaf(e1.z, w.y, a1y[2]);
            a0x[3] = fmaf(e0.w, w.x, a0x[3]); a0y[3] = fmaf(e0.w, w.y, a0y[3]);
            a1x[3] = fmaf(e1.w, w.x, a1x[3]); a1y[3] = fmaf(e1.w, w.y, a1y[3]);
        }
        #pragma unroll
        for (int mm = 0; mm < 4; ++mm) {
            hs00 += fmaxf(a0x[mm], 0.f); hs01 += fmaxf(a0y[mm], 0.f);
            hs10 += fmaxf(a1x[mm], 0.f); hs11 += fmaxf(a1y[mm], 0.f);
        }
    }
    s_h[na][j0] = hs00; s_h[na][j0 + 1] = hs01;
    s_h[nb][j0] = hs10; s_h[nb][j0 + 1] = hs11;
    __syncthreads();

    // ---- stage 2: t1 = relu(hsum @ Wf1 + bf1) ----
    {
        const float2 bf = *(const float2*)&bf1[j0];
        float a00 = bf.x, a01 = bf.y, a10 = bf.x, a11 = bf.y;
        for (int k = 0; k < H; k += 4) {
            const float2 w0 = *(const float2*)&Wf1[(k    ) * H + j0];
            const float2 w1v= *(const float2*)&Wf1[(k + 1) * H + j0];
            const float2 w2v= *(const float2*)&Wf1[(k + 2) * H + j0];
            const float2 w3v= *(const float2*)&Wf1[(k + 3) * H + j0];
            const float4 h0 = *(const float4*)&s_h[na][k];
            const float4 h1 = *(const float4*)&s_h[nb][k];
            a00 = fmaf(h0.x, w0.x,  a00); a01 = fmaf(h0.x, w0.y,  a01);
            a10 = fmaf(h1.x, w0.x,  a10); a11 = fmaf(h1.x, w0.y,  a11);
            a00 = fmaf(h0.y, w1v.x, a00); a01 = fmaf(h0.y, w1v.y, a01);
            a10 = fmaf(h1.y, w1v.x, a10); a11 = fmaf(h1.y, w1v.y, a11);
            a00 = fmaf(h0.z, w2v.x, a00); a01 = fmaf(h0.z, w2v.y, a01);
            a10 = fmaf(h1.z, w2v.x, a10); a11 = fmaf(h1.z, w2v.y, a11);
            a00 = fmaf(h0.w, w3v.x, a00); a01 = fmaf(h0.w, w3v.y, a01);
            a10 = fmaf(h1.w, w3v.x, a10); a11 = fmaf(h1.w, w3v.y, a11);
        }
        s_t[na][j0] = fmaxf(a00, 0.f); s_t[na][j0 + 1] = fmaxf(a01, 0.f);
        s_t[nb][j0] = fmaxf(a10, 0.f); s_t[nb][j0 + 1] = fmaxf(a11, 0.f);
    }
    __syncthreads();

    // ---- stage 3: h = t1 @ Wf2 + x @ dr_w[:32] + bf2 ----
    {
        const float2 bf = *(const float2*)&bf2[j0];
        float a00 = bf.x, a01 = bf.y, a10 = bf.x, a11 = bf.y;
        for (int k = 0; k < H; k += 4) {
            const float2 w0 = *(const float2*)&Wf2[(k    ) * H + j0];
            const float2 w1v= *(const float2*)&Wf2[(k + 1) * H + j0];
            const float2 w2v= *(const float2*)&Wf2[(k + 2) * H + j0];
            const float2 w3v= *(const float2*)&Wf2[(k + 3) * H + j0];
            const float4 t0 = *(const float4*)&s_t[na][k];
            const float4 t1 = *(const float4*)&s_t[nb][k];
            a00 = fmaf(t0.x, w0.x,  a00); a01 = fmaf(t0.x, w0.y,  a01);
            a10 = fmaf(t1.x, w0.x,  a10); a11 = fmaf(t1.x, w0.y,  a11);
            a00 = fmaf(t0.y, w1v.x, a00); a01 = fmaf(t0.y, w1v.y, a01);
            a10 = fmaf(t1.y, w1v.x, a10); a11 = fmaf(t1.y, w1v.y, a11);
            a00 = fmaf(t0.z, w2v.x, a00); a01 = fmaf(t0.z, w2v.y, a01);
            a10 = fmaf(t1.z, w2v.x, a10); a11 = fmaf(t1.z, w2v.y, a11);
            a00 = fmaf(t0.w, w3v.x, a00); a01 = fmaf(t0.w, w3v.y, a01);
            a10 = fmaf(t1.w, w3v.x, a10); a11 = fmaf(t1.w, w3v.y, a11);
        }
        #pragma unroll
        for (int k = 0; k < C_IN; k += 4) {
            const float2 w0 = *(const float2*)&dr_w[(k    ) * H + j0];
            const float2 w1v= *(const float2*)&dr_w[(k + 1) * H + j0];
            const float2 w2v= *(const float2*)&dr_w[(k + 2) * H + j0];
            const float2 w3v= *(const float2*)&dr_w[(k + 3) * H + j0];
            const float4 x0 = *(const float4*)&s_x[na][k];
            const float4 x1 = *(const float4*)&s_x[nb][k];
            a00 = fmaf(x0.x, w0.x,  a00); a01 = fmaf(x0.x, w0.y,  a01);
            a10 = fmaf(x1.x, w0.x,  a10); a11 = fmaf(x1.x, w0.y,  a11);
            a00 = fmaf(x0.y, w1v.x, a00); a01 = fmaf(x0.y, w1v.y, a01);
            a10 = fmaf(x1.y, w1v.x, a10); a11 = fmaf(x1.y, w1v.y, a11);
            a00 = fmaf(x0.z, w2v.x, a00); a01 = fmaf(x0.z, w2v.y, a01);
            a10 = fmaf(x1.z, w2v.x, a10); a11 = fmaf(x1.z, w2v.y, a11);
            a00 = fmaf(x0.w, w3v.x, a00); a01 = fmaf(x0.w, w3v.y, a01);
            a10 = fmaf(x1.w, w3v.x, a10); a11 = fmaf(x1.w, w3v.y, a11);
        }
        float2 ra; ra.x = a00; ra.y = a01;
        float2 rb2v; rb2v.x = a10; rb2v.y = a11;
        *(float2*)&h_out[(size_t)(n0 + na) * H + j0] = ra;
        *(float2*)&h_out[(size_t)(n0 + nb) * H + j0] = rb2v;
    }
}

// ---------------------------------------------------------------------------
// CSR build. csr entries packed as int2{src, float_bits(edge_attr)}.
// ---------------------------------------------------------------------------
__global__ __launch_bounds__(256) void k_count(
    const int* __restrict__ ei, int* __restrict__ deg)
{
    const int e = blockIdx.x * 256 + threadIdx.x;
    if (e >= E_EDGES) return;
    atomicAdd(&deg[ei[E_EDGES + e]], 1);
}

__global__ __launch_bounds__(1024) void k_scan(
    int* __restrict__ off, int* __restrict__ cursor)
{
    const int t = threadIdx.x;
    const int CHUNK = (N_NODES + 1023) / 1024;
    const int lo = t * CHUNK;
    const int hi = min(lo + CHUNK, N_NODES);

    int mysum = 0;
    for (int i = lo; i < hi; ++i) mysum += off[i];

    __shared__ int s[1024];
    s[t] = mysum;
    __syncthreads();
    for (int d = 1; d < 1024; d <<= 1) {
        int v = (t >= d) ? s[t - d] : 0;
        __syncthreads();
        s[t] += v;
        __syncthreads();
    }
    int running = s[t] - mysum;

    for (int i = lo; i < hi; ++i) {
        const int d = off[i];
        off[i] = running;
        cursor[i] = running;
        running += d;
    }
    if (t == 0) off[N_NODES] = E_EDGES;
}

__global__ __launch_bounds__(256) void k_fill(
    const int* __restrict__ ei, const float* __restrict__ ea,
    int* __restrict__ cursor, int2* __restrict__ csr)
{
    const int e = blockIdx.x * 256 + threadIdx.x;
    if (e >= E_EDGES) return;
    const int dst = ei[E_EDGES + e];
    const int pos = atomicAdd(&cursor[dst], 1);
    csr[pos] = make_int2(ei[e], __float_as_int(ea[e]));
}

// ---------------------------------------------------------------------------
// k_agg: CSR gather aggregation.
// One wave per node; half0 takes edges [s,mid), half1 [mid,e). 8-deep unroll
// -> 16 outstanding 512B gathers per wave. Cross-half combine via shfl_xor(32).
// ---------------------------------------------------------------------------
__global__ __launch_bounds__(256) void k_agg(
    const int* __restrict__ off, const int2* __restrict__ csr,
    const float* __restrict__ h, const float* __restrict__ ew,
    const float* __restrict__ eb, float* __restrict__ agg)
{
    const int wave = threadIdx.x >> 6;
    const int lane = threadIdx.x & 63;
    const int half = lane >> 5;
    const int c = (lane & 31) * 4;
    const int n = blockIdx.x * 4 + wave;

    const float4 wv = *(const float4*)&ew[c];
    const float4 bv = *(const float4*)&eb[c];

    const int s = off[n], e = off[n + 1];
    const int mid = s + ((e - s + 1) >> 1);
    int i        = half ? mid : s;
    const int hi = half ? e   : mid;

    float ax0 = 0.f, ay0 = 0.f, az0 = 0.f, aw0 = 0.f;
    float ax1 = 0.f, ay1 = 0.f, az1 = 0.f, aw1 = 0.f;

    for (; i + 7 < hi; i += 8) {
        int2 p[8];
        #pragma unroll
        for (int u = 0; u < 8; ++u) p[u] = csr[i + u];
        float4 hv[8];
        #pragma unroll
        for (int u = 0; u < 8; ++u)
            hv[u] = *(const float4*)&h[(size_t)p[u].x * H + c];
        #pragma unroll
        for (int u = 0; u < 8; ++u) {
            const float a = __int_as_float(p[u].y);
            if (u & 1) {
                ax1 += fmaxf(fmaf(a, wv.x, hv[u].x) + bv.x, 0.f);
                ay1 += fmaxf(fmaf(a, wv.y, hv[u].y) + bv.y, 0.f);
                az1 += fmaxf(fmaf(a, wv.z, hv[u].z) + bv.z, 0.f);
                aw1 += fmaxf(fmaf(a, wv.w, hv[u].w) + bv.w, 0.f);
            } else {
                ax0 += fmaxf(fmaf(a, wv.x, hv[u].x) + bv.x, 0.f);
                ay0 += fmaxf(fmaf(a, wv.y, hv[u].y) + bv.y, 0.f);
                az0 += fmaxf(fmaf(a, wv.z, hv[u].z) + bv.z, 0.f);
                aw0 += fmaxf(fmaf(a, wv.w, hv[u].w) + bv.w, 0.f);
            }
        }
    }
    for (; i + 3 < hi; i += 4) {
        const int2 p0 = csr[i];
        const int2 p1 = csr[i + 1];
        const int2 p2 = csr[i + 2];
        const int2 p3 = csr[i + 3];
        const float4 h0 = *(const float4*)&h[(size_t)p0.x * H + c];
        const float4 h1 = *(const float4*)&h[(size_t)p1.x * H + c];
        const float4 h2 = *(const float4*)&h[(size_t)p2.x * H + c];
        const float4 h3 = *(const float4*)&h[(size_t)p3.x * H + c];
        const float a0 = __int_as_float(p0.y);
        const float a1 = __int_as_float(p1.y);
        const float a2 = __int_as_float(p2.y);
        const float a3 = __int_as_float(p3.y);
        ax0 += fmaxf(fmaf(a0, wv.x, h0.x) + bv.x, 0.f);
        ay0 += fmaxf(fmaf(a0, wv.y, h0.y) + bv.y, 0.f);
        az0 += fmaxf(fmaf(a0, wv.z, h0.z) + bv.z, 0.f);
        aw0 += fmaxf(fmaf(a0, wv.w, h0.w) + bv.w, 0.f);
        ax1 += fmaxf(fmaf(a1, wv.x, h1.x) + bv.x, 0.f);
        ay1 += fmaxf(fmaf(a1, wv.y, h1.y) + bv.y, 0.f);
        az1 += fmaxf(fmaf(a1, wv.z, h1.z) + bv.z, 0.f);
        aw1 += fmaxf(fmaf(a1, wv.w, h1.w) + bv.w, 0.f);
        ax0 += fmaxf(fmaf(a2, wv.x, h2.x) + bv.x, 0.f);
        ay0 += fmaxf(fmaf(a2, wv.y, h2.y) + bv.y, 0.f);
        az0 += fmaxf(fmaf(a2, wv.z, h2.z) + bv.z, 0.f);
        aw0 += fmaxf(fmaf(a2, wv.w, h2.w) + bv.w, 0.f);
        ax1 += fmaxf(fmaf(a3, wv.x, h3.x) + bv.x, 0.f);
        ay1 += fmaxf(fmaf(a3, wv.y, h3.y) + bv.y, 0.f);
        az1 += fmaxf(fmaf(a3, wv.z, h3.z) + bv.z, 0.f);
        aw1 += fmaxf(fmaf(a3, wv.w, h3.w) + bv.w, 0.f);
    }
    for (; i < hi; ++i) {
        const int2 p0 = csr[i];
        const float4 h0 = *(const float4*)&h[(size_t)p0.x * H + c];
        const float a0 = __int_as_float(p0.y);
        ax0 += fmaxf(fmaf(a0, wv.x, h0.x) + bv.x, 0.f);
        ay0 += fmaxf(fmaf(a0, wv.y, h0.y) + bv.y, 0.f);
        az0 += fmaxf(fmaf(a0, wv.z, h0.z) + bv.z, 0.f);
        aw0 += fmaxf(fmaf(a0, wv.w, h0.w) + bv.w, 0.f);
    }
    ax0 += ax1; ay0 += ay1; az0 += az1; aw0 += aw1;
    ax0 += __shfl_xor(ax0, 32);
    ay0 += __shfl_xor(ay0, 32);
    az0 += __shfl_xor(az0, 32);
    aw0 += __shfl_xor(aw0, 32);
    if (half == 0) {
        float4 r; r.x = ax0; r.y = ay0; r.z = az0; r.w = aw0;
        *(float4*)&agg[(size_t)n * H + c] = r;
    }
}

// ---------------------------------------------------------------------------
// k_gine: node update; float4 LDS reads, float2 weight rows.
// ---------------------------------------------------------------------------
#define NPB 8
__global__ __launch_bounds__(256) void k_gine(
    const float* __restrict__ agg, float* __restrict__ h,
    const float* __restrict__ eps_p,
    const float* __restrict__ w1, const float* __restrict__ b1,
    const float* __restrict__ bn_g, const float* __restrict__ bn_b,
    const float* __restrict__ bn_m, const float* __restrict__ bn_v,
    const float* __restrict__ w2, const float* __restrict__ b2,
    const int first_layer)
{
    const int n0 = blockIdx.x * NPB;
    const int t  = threadIdx.x;
    const int jp = t & 63;  const int j0 = jp * 2;
    const int np = t >> 6;  const int na = np * 2, nb = na + 1;

    __shared__ __align__(16) float s_z[NPB][H];
    __shared__ __align__(16) float s_t[NPB][H];
    __shared__ __align__(16) float s_r[NPB][H];

    const float ep1 = 1.f + eps_p[0];

    for (int i = t; i < NPB * H; i += 256) {
        const int q = i >> 7, c = i & 127;
        const int n = n0 + q;
        const float hv = h[(size_t)n * H + c];
        const float av = agg[(size_t)n * H + c];
        s_r[q][c] = hv;
        s_z[q][c] = fmaf(ep1, hv, av);
    }
    __syncthreads();

    {
        const float2 g = *(const float2*)&bn_g[j0];
        const float2 b = *(const float2*)&bn_b[j0];
        const float2 m = *(const float2*)&bn_m[j0];
        const float2 v = *(const float2*)&bn_v[j0];
        const float2 bb = *(const float2*)&b1[j0];
        const float scx = g.x * rsqrtf(v.x + BN_EPS);
        const float scy = g.y * rsqrtf(v.y + BN_EPS);
        const float shx = fmaf(bb.x - m.x, scx, b.x);
        const float shy = fmaf(bb.y - m.y, scy, b.y);

        float a00 = 0.f, a01 = 0.f, a10 = 0.f, a11 = 0.f;
        for (int k = 0; k < H; k += 4) {
            const float2 w0 = *(const float2*)&w1[(k    ) * H + j0];
            const float2 w1v= *(const float2*)&w1[(k + 1) * H + j0];
            const float2 w2v= *(const float2*)&w1[(k + 2) * H + j0];
            const float2 w3v= *(const float2*)&w1[(k + 3) * H + j0];
            const float4 z0 = *(const float4*)&s_z[na][k];
            const float4 z1 = *(const float4*)&s_z[nb][k];
            a00 = fmaf(z0.x, w0.x,  a00); a01 = fmaf(z0.x, w0.y,  a01);
            a10 = fmaf(z1.x, w0.x,  a10); a11 = fmaf(z1.x, w0.y,  a11);
            a00 = fmaf(z0.y, w1v.x, a00); a01 = fmaf(z0.y, w1v.y, a01);
            a10 = fmaf(z1.y, w1v.x, a10); a11 = fmaf(z1.y, w1v.y, a11);
            a00 = fmaf(z0.z, w2v.x, a00); a01 = fmaf(z0.z, w2v.y, a01);
            a10 = fmaf(z1.z, w2v.x, a10); a11 = fmaf(z1.z, w2v.y, a11);
            a00 = fmaf(z0.w, w3v.x, a00); a01 = fmaf(z0.w, w3v.y, a01);
            a10 = fmaf(z1.w, w3v.x, a10); a11 = fmaf(z1.w, w3v.y, a11);
        }
        s_t[na][j0]     = fmaxf(fmaf(a00, scx, shx), 0.f);
        s_t[na][j0 + 1] = fmaxf(fmaf(a01, scy, shy), 0.f);
        s_t[nb][j0]     = fmaxf(fmaf(a10, scx, shx), 0.f);
        s_t[nb][j0 + 1] = fmaxf(fmaf(a11, scy, shy), 0.f);
    }
    __syncthreads();

    {
        const float2 bb = *(const float2*)&b2[j0];
        float a00 = bb.x, a01 = bb.y, a10 = bb.x, a11 = bb.y;
        for (int k = 0; k < H; k += 4) {
            const float2 w0 = *(const float2*)&w2[(k    ) * H + j0];
            const float2 w1v= *(const float2*)&w2[(k + 1) * H + j0];
            const float2 w2v= *(const float2*)&w2[(k + 2) * H + j0];
            const float2 w3v= *(const float2*)&w2[(k + 3) * H + j0];
            const float4 t0 = *(const float4*)&s_t[na][k];
            const float4 t1 = *(const float4*)&s_t[nb][k];
            a00 = fmaf(t0.x, w0.x,  a00); a01 = fmaf(t0.x, w0.y,  a01);
            a10 = fmaf(t1.x, w0.x,  a10); a11 = fmaf(t1.x, w0.y,  a11);
            a00 = fmaf(t0.y, w1v.x, a00); a01 = fmaf(t0.y, w1v.y, a01);
            a10 = fmaf(t1.y, w1v.x, a10); a11 = fmaf(t1.y, w1v.y, a11);
            a00 = fmaf(t0.z, w2v.x, a00); a01 = fmaf(t0.z, w2v.y, a01);
            a10 = fmaf(t1.z, w2v.x, a10); a11 = fmaf(t1.z, w2v.y, a11);
            a00 = fmaf(t0.w, w3v.x, a00); a01 = fmaf(t0.w, w3v.y, a01);
            a10 = fmaf(t1.w, w3v.x, a10); a11 = fmaf(t1.w, w3v.y, a11);
        }
        float2 ra, rb;
        if (first_layer) {
            ra.x = fmaxf(a00, 0.f); ra.y = fmaxf(a01, 0.f);
            rb.x = fmaxf(a10, 0.f); rb.y = fmaxf(a11, 0.f);
        } else {
            ra.x = s_r[na][j0]     + fmaxf(a00, 0.f);
            ra.y = s_r[na][j0 + 1] + fmaxf(a01, 0.f);
            rb.x = s_r[nb][j0]     + fmaxf(a10, 0.f);
            rb.y = s_r[nb][j0 + 1] + fmaxf(a11, 0.f);
        }
        *(float2*)&h[(size_t)(n0 + na) * H + j0] = ra;
        *(float2*)&h[(size_t)(n0 + nb) * H + j0] = rb;
    }
}

// ---------------------------------------------------------------------------
// k_out: output head (unchanged).
// ---------------------------------------------------------------------------
__global__ __launch_bounds__(256) void k_out(
    const float* __restrict__ h, const float* __restrict__ aw,
    const float* __restrict__ ab, float* __restrict__ out)
{
    const int n = blockIdx.x * 2 + (threadIdx.x >> 7);
    const int j = threadIdx.x & 127;
    const int base = (threadIdx.x >> 7) << 7;

    __shared__ float r0[256];
    __shared__ float r1[256];

    const float hv = h[(size_t)n * H + j];
    r0[threadIdx.x] = hv * aw[j * 2 + 0];
    r1[threadIdx.x] = hv * aw[j * 2 + 1];
    __syncthreads();

    for (int s = 64; s > 0; s >>= 1) {
        if (j < s) {
            r0[base + j] += r0[base + j + s];
            r1[base + j] += r1[base + j + s];
        }
        __syncthreads();
    }
    if (j == 0) {
        const float mu = r0[base] + ab[0];
        const float o1 = r1[base] + ab[1];
        const float sp = (o1 > 0.f) ? (o1 + log1pf(expf(-o1)))
                                    : log1pf(expf(o1));
        out[(size_t)n * 2 + 0] = mu;
        out[(size_t)n * 2 + 1] = sp;
    }
}

// ---------------------------------------------------------------------------
extern "C" void kernel_launch(void* const* d_in, const int* in_sizes, int n_in,
                              void* d_out, int out_size, void* d_ws, size_t ws_size,
                              hipStream_t stream)
{
    const float* ensemble = (const float*)d_in[0];
    const float* x        = (const float*)d_in[1];
    const int*   ei       = (const int*)d_in[2];
    const float* ea       = (const float*)d_in[3];
    const float* phi_w1   = (const float*)d_in[4];
    const float* phi_b1   = (const float*)d_in[5];
    const float* phi_w2   = (const float*)d_in[6];
    const float* phi_b2   = (const float*)d_in[7];
    const float* rho_w1   = (const float*)d_in[8];
    const float* rho_b1   = (const float*)d_in[9];
    const float* rho_w2   = (const float*)d_in[10];
    const float* rho_b2   = (const float*)d_in[11];
    const float* dr_w     = (const float*)d_in[12];
    const float* dr_b     = (const float*)d_in[13];
    const float* conv_eps = (const float*)d_in[14];
    const float* edge_w   = (const float*)d_in[15];
    const float* edge_b   = (const float*)d_in[16];
    const float* mlp_w1   = (const float*)d_in[17];
    const float* mlp_b1   = (const float*)d_in[18];
    const float* bn_g     = (const float*)d_in[19];
    const float* bn_b     = (const float*)d_in[20];
    const float* bn_m     = (const float*)d_in[21];
    const float* bn_v     = (const float*)d_in[22];
    const float* mlp_w2   = (const float*)d_in[23];
    const float* mlp_b2   = (const float*)d_in[24];
    const float* aggr_w   = (const float*)d_in[25];
    const float* aggr_b   = (const float*)d_in[26];

    float* out = (float*)d_out;

    // workspace layout (int2 csr needs 8B alignment -> pad off to even count)
    float* h_buf   = (float*)d_ws;                          // N*H
    float* agg_buf = h_buf + (size_t)N_NODES * H;           // N*H
    float* Wf1     = agg_buf + (size_t)N_NODES * H;         // H*H
    float* bf1     = Wf1 + H * H;                           // H
    float* Wf2     = bf1 + H;                               // H*H
    float* bf2     = Wf2 + H * H;                           // H
    int*   off     = (int*)(bf2 + H);                       // N+2 (padded)
    int*   cursor  = off + (N_NODES + 2);                   // N
    int2*  csr     = (int2*)(cursor + N_NODES);             // E (8B aligned)

    const int eblocks = (E_EDGES + 255) / 256;

    // fold weights, then embed
    k_fold<<<256, 256, 0, stream>>>(phi_w2, phi_b2, rho_w1, rho_b1,
                                    rho_w2, rho_b2, dr_w, dr_b,
                                    Wf1, bf1, Wf2, bf2);
    k_embed<<<N_NODES / ENB, 256, 0, stream>>>(
        ensemble, x, phi_w1, phi_b1, Wf1, bf1, Wf2, bf2, dr_w, h_buf);

    // CSR build (once)
    hipMemsetAsync(off, 0, (N_NODES + 1) * sizeof(int), stream);
    k_count<<<eblocks, 256, 0, stream>>>(ei, off);
    k_scan<<<1, 1024, 0, stream>>>(off, cursor);
    k_fill<<<eblocks, 256, 0, stream>>>(ei, ea, cursor, csr);

    // GINE layers
    for (int i = 0; i < L_LAYERS; ++i) {
        k_agg<<<N_NODES / 4, 256, 0, stream>>>(
            off, csr, h_buf,
            edge_w + (size_t)i * H, edge_b + (size_t)i * H, agg_buf);
        k_gine<<<N_NODES / NPB, 256, 0, stream>>>(
            agg_buf, h_buf, conv_eps + i,
            mlp_w1 + (size_t)i * H * H, mlp_b1 + (size_t)i * H,
            bn_g + (size_t)i * H, bn_b + (size_t)i * H,
            bn_m + (size_t)i * H, bn_v + (size_t)i * H,
            mlp_w2 + (size_t)i * H * H, mlp_b2 + (size_t)i * H,
            (i == 0) ? 1 : 0);
    }

    k_out<<<N_NODES / 2, 256, 0, stream>>>(h_buf, aggr_w, aggr_b, out);
}

// Round 7
// 1407.950 us; speedup vs baseline: 1.0710x; 1.0710x over previous
//
#include <hip/hip_runtime.h>
#include <math.h>

#define N_NODES 50000
#define M_ENS   20
#define C_IN    32
#define H       128
#define E_EDGES 800000
#define L_LAYERS 3
#define BN_EPS  1e-5f

typedef unsigned short u16;
typedef unsigned int   u32;

// bf16 helpers (RNE pack, cheap unpack)
__device__ __forceinline__ float bf_lo(u32 p) {
    union { u32 u; float f; } v; v.u = p << 16; return v.f;
}
__device__ __forceinline__ float bf_hi(u32 p) {
    union { u32 u; float f; } v; v.u = p & 0xFFFF0000u; return v.f;
}
__device__ __forceinline__ u16 f2bf(float f) {
    union { float f; u32 u; } v; v.f = f;
    const u32 r = v.u + 0x7FFFu + ((v.u >> 16) & 1u);
    return (u16)(r >> 16);
}
__device__ __forceinline__ u32 pack2bf(float a, float b) {
    return (u32)f2bf(a) | ((u32)f2bf(b) << 16);
}

// ---------------------------------------------------------------------------
// k_fold: precompute folded weights (once per launch):
//   g=0: Wf1 = phi_w2 @ rho_w1,            bf1 = 20*phi_b2 @ rho_w1 + rho_b1
//   g=1: Wf2 = rho_w2 @ dr_w[32:],         bf2 = rho_b2 @ dr_w[32:] + dr_b
// ---------------------------------------------------------------------------
__global__ __launch_bounds__(256) void k_fold(
    const float* __restrict__ w2,  const float* __restrict__ b2,
    const float* __restrict__ rw1, const float* __restrict__ rb1,
    const float* __restrict__ rw2, const float* __restrict__ rb2,
    const float* __restrict__ dr_w, const float* __restrict__ dr_b,
    float* __restrict__ Wf1, float* __restrict__ bf1,
    float* __restrict__ Wf2, float* __restrict__ bf2)
{
    const int g = blockIdx.x >> 7;
    const int j = blockIdx.x & 127;
    const int t = threadIdx.x;

    const float* A  = g ? rw2 : w2;
    const float* Bm = g ? (dr_w + C_IN * H) : rw1;

    __shared__ float s_col[H];
    if (t < H) s_col[t] = Bm[t * H + j];
    __syncthreads();

    const int r = t >> 1, q = t & 1;
    const float* arow = &A[r * H + q * 64];
    const float* cp = &s_col[q * 64];
    float acc = 0.f;
    #pragma unroll
    for (int u = 0; u < 64; u += 4) {
        const float4 av = *(const float4*)&arow[u];
        acc = fmaf(av.x, cp[u], acc);
        acc = fmaf(av.y, cp[u + 1], acc);
        acc = fmaf(av.z, cp[u + 2], acc);
        acc = fmaf(av.w, cp[u + 3], acc);
    }
    acc += __shfl_xor(acc, 1);
    if (q == 0) (g ? Wf2 : Wf1)[r * H + j] = acc;

    if (t == 0) {
        float bacc = g ? dr_b[j] : rb1[j];
        const float* bsrc = g ? rb2 : b2;
        const float scale = g ? 1.f : 20.f;
        for (int k = 0; k < H; ++k)
            bacc = fmaf(scale * bsrc[k], s_col[k], bacc);
        (g ? bf2 : bf1)[j] = bacc;
    }
}

// ---------------------------------------------------------------------------
// k_embed: R4 structure (best measured: 312us). Only change: bf16 h store.
// ---------------------------------------------------------------------------
#define ENB 8
__global__ __launch_bounds__(256) void k_embed(
    const float* __restrict__ ensemble, const float* __restrict__ x,
    const float* __restrict__ phi_w1,   const float* __restrict__ phi_b1,
    const float* __restrict__ Wf1, const float* __restrict__ bf1,
    const float* __restrict__ Wf2, const float* __restrict__ bf2,
    const float* __restrict__ dr_w,
    u16* __restrict__ h_out)
{
    const int n0 = blockIdx.x * ENB;
    const int t  = threadIdx.x;
    const int jp = t & 63;  const int j0 = jp * 2;
    const int np = t >> 6;  const int na = np * 2, nb = na + 1;

    __shared__ __align__(16) float s_ens[ENB * M_ENS * C_IN];
    __shared__ __align__(16) float s_h[ENB][H];
    __shared__ __align__(16) float s_t[ENB][H];
    __shared__ __align__(16) float s_x[ENB][C_IN];

    for (int i = t; i < ENB * M_ENS * C_IN; i += 256)
        s_ens[i] = ensemble[(size_t)n0 * (M_ENS * C_IN) + i];
    s_x[t >> 5][t & 31] = x[(size_t)n0 * C_IN + t];
    __syncthreads();

    float w1a[C_IN], w1b[C_IN];
    #pragma unroll
    for (int k = 0; k < C_IN; ++k) {
        w1a[k] = phi_w1[k * H + j0];
        w1b[k] = phi_w1[k * H + j0 + 1];
    }
    const float b1a = phi_b1[j0], b1b = phi_b1[j0 + 1];

    // ---- stage 1: hsum = sum_m relu(ens_m @ w1 + b1) ----
    float hs00 = 0.f, hs01 = 0.f, hs10 = 0.f, hs11 = 0.f;
    for (int m = 0; m < M_ENS; ++m) {
        float a00 = b1a, a01 = b1b, a10 = b1a, a11 = b1b;
        const float* ea = &s_ens[(na * M_ENS + m) * C_IN];
        const float* eb = &s_ens[(nb * M_ENS + m) * C_IN];
        #pragma unroll
        for (int k = 0; k < C_IN; k += 4) {
            const float4 e0 = *(const float4*)&ea[k];
            const float4 e1 = *(const float4*)&eb[k];
            a00 = fmaf(e0.x, w1a[k],   a00); a01 = fmaf(e0.x, w1b[k],   a01);
            a10 = fmaf(e1.x, w1a[k],   a10); a11 = fmaf(e1.x, w1b[k],   a11);
            a00 = fmaf(e0.y, w1a[k+1], a00); a01 = fmaf(e0.y, w1b[k+1], a01);
            a10 = fmaf(e1.y, w1a[k+1], a10); a11 = fmaf(e1.y, w1b[k+1], a11);
            a00 = fmaf(e0.z, w1a[k+2], a00); a01 = fmaf(e0.z, w1b[k+2], a01);
            a10 = fmaf(e1.z, w1a[k+2], a10); a11 = fmaf(e1.z, w1b[k+2], a11);
            a00 = fmaf(e0.w, w1a[k+3], a00); a01 = fmaf(e0.w, w1b[k+3], a01);
            a10 = fmaf(e1.w, w1a[k+3], a10); a11 = fmaf(e1.w, w1b[k+3], a11);
        }
        hs00 += fmaxf(a00, 0.f); hs01 += fmaxf(a01, 0.f);
        hs10 += fmaxf(a10, 0.f); hs11 += fmaxf(a11, 0.f);
    }
    s_h[na][j0] = hs00; s_h[na][j0 + 1] = hs01;
    s_h[nb][j0] = hs10; s_h[nb][j0 + 1] = hs11;
    __syncthreads();

    // ---- stage 2: t1 = relu(hsum @ Wf1 + bf1) ----
    {
        const float2 bf = *(const float2*)&bf1[j0];
        float a00 = bf.x, a01 = bf.y, a10 = bf.x, a11 = bf.y;
        for (int k = 0; k < H; k += 4) {
            const float2 w0 = *(const float2*)&Wf1[(k    ) * H + j0];
            const float2 w1v= *(const float2*)&Wf1[(k + 1) * H + j0];
            const float2 w2v= *(const float2*)&Wf1[(k + 2) * H + j0];
            const float2 w3v= *(const float2*)&Wf1[(k + 3) * H + j0];
            const float4 h0 = *(const float4*)&s_h[na][k];
            const float4 h1 = *(const float4*)&s_h[nb][k];
            a00 = fmaf(h0.x, w0.x,  a00); a01 = fmaf(h0.x, w0.y,  a01);
            a10 = fmaf(h1.x, w0.x,  a10); a11 = fmaf(h1.x, w0.y,  a11);
            a00 = fmaf(h0.y, w1v.x, a00); a01 = fmaf(h0.y, w1v.y, a01);
            a10 = fmaf(h1.y, w1v.x, a10); a11 = fmaf(h1.y, w1v.y, a11);
            a00 = fmaf(h0.z, w2v.x, a00); a01 = fmaf(h0.z, w2v.y, a01);
            a10 = fmaf(h1.z, w2v.x, a10); a11 = fmaf(h1.z, w2v.y, a11);
            a00 = fmaf(h0.w, w3v.x, a00); a01 = fmaf(h0.w, w3v.y, a01);
            a10 = fmaf(h1.w, w3v.x, a10); a11 = fmaf(h1.w, w3v.y, a11);
        }
        s_t[na][j0] = fmaxf(a00, 0.f); s_t[na][j0 + 1] = fmaxf(a01, 0.f);
        s_t[nb][j0] = fmaxf(a10, 0.f); s_t[nb][j0 + 1] = fmaxf(a11, 0.f);
    }
    __syncthreads();

    // ---- stage 3: h = t1 @ Wf2 + x @ dr_w[:32] + bf2 ----
    {
        const float2 bf = *(const float2*)&bf2[j0];
        float a00 = bf.x, a01 = bf.y, a10 = bf.x, a11 = bf.y;
        for (int k = 0; k < H; k += 4) {
            const float2 w0 = *(const float2*)&Wf2[(k    ) * H + j0];
            const float2 w1v= *(const float2*)&Wf2[(k + 1) * H + j0];
            const float2 w2v= *(const float2*)&Wf2[(k + 2) * H + j0];
            const float2 w3v= *(const float2*)&Wf2[(k + 3) * H + j0];
            const float4 t0 = *(const float4*)&s_t[na][k];
            const float4 t1 = *(const float4*)&s_t[nb][k];
            a00 = fmaf(t0.x, w0.x,  a00); a01 = fmaf(t0.x, w0.y,  a01);
            a10 = fmaf(t1.x, w0.x,  a10); a11 = fmaf(t1.x, w0.y,  a11);
            a00 = fmaf(t0.y, w1v.x, a00); a01 = fmaf(t0.y, w1v.y, a01);
            a10 = fmaf(t1.y, w1v.x, a10); a11 = fmaf(t1.y, w1v.y, a11);
            a00 = fmaf(t0.z, w2v.x, a00); a01 = fmaf(t0.z, w2v.y, a01);
            a10 = fmaf(t1.z, w2v.x, a10); a11 = fmaf(t1.z, w2v.y, a11);
            a00 = fmaf(t0.w, w3v.x, a00); a01 = fmaf(t0.w, w3v.y, a01);
            a10 = fmaf(t1.w, w3v.x, a10); a11 = fmaf(t1.w, w3v.y, a11);
        }
        #pragma unroll
        for (int k = 0; k < C_IN; k += 4) {
            const float2 w0 = *(const float2*)&dr_w[(k    ) * H + j0];
            const float2 w1v= *(const float2*)&dr_w[(k + 1) * H + j0];
            const float2 w2v= *(const float2*)&dr_w[(k + 2) * H + j0];
            const float2 w3v= *(const float2*)&dr_w[(k + 3) * H + j0];
            const float4 x0 = *(const float4*)&s_x[na][k];
            const float4 x1 = *(const float4*)&s_x[nb][k];
            a00 = fmaf(x0.x, w0.x,  a00); a01 = fmaf(x0.x, w0.y,  a01);
            a10 = fmaf(x1.x, w0.x,  a10); a11 = fmaf(x1.x, w0.y,  a11);
            a00 = fmaf(x0.y, w1v.x, a00); a01 = fmaf(x0.y, w1v.y, a01);
            a10 = fmaf(x1.y, w1v.x, a10); a11 = fmaf(x1.y, w1v.y, a11);
            a00 = fmaf(x0.z, w2v.x, a00); a01 = fmaf(x0.z, w2v.y, a01);
            a10 = fmaf(x1.z, w2v.x, a10); a11 = fmaf(x1.z, w2v.y, a11);
            a00 = fmaf(x0.w, w3v.x, a00); a01 = fmaf(x0.w, w3v.y, a01);
            a10 = fmaf(x1.w, w3v.x, a10); a11 = fmaf(x1.w, w3v.y, a11);
        }
        *(u32*)&h_out[(size_t)(n0 + na) * H + j0] = pack2bf(a00, a01);
        *(u32*)&h_out[(size_t)(n0 + nb) * H + j0] = pack2bf(a10, a11);
    }
}

// ---------------------------------------------------------------------------
// CSR build. csr entries packed as int2{src, float_bits(edge_attr)}.
// ---------------------------------------------------------------------------
__global__ __launch_bounds__(256) void k_count(
    const int* __restrict__ ei, int* __restrict__ deg)
{
    const int e = blockIdx.x * 256 + threadIdx.x;
    if (e >= E_EDGES) return;
    atomicAdd(&deg[ei[E_EDGES + e]], 1);
}

__global__ __launch_bounds__(1024) void k_scan(
    int* __restrict__ off, int* __restrict__ cursor)
{
    const int t = threadIdx.x;
    const int CHUNK = (N_NODES + 1023) / 1024;
    const int lo = t * CHUNK;
    const int hi = min(lo + CHUNK, N_NODES);

    int mysum = 0;
    for (int i = lo; i < hi; ++i) mysum += off[i];

    __shared__ int s[1024];
    s[t] = mysum;
    __syncthreads();
    for (int d = 1; d < 1024; d <<= 1) {
        int v = (t >= d) ? s[t - d] : 0;
        __syncthreads();
        s[t] += v;
        __syncthreads();
    }
    int running = s[t] - mysum;

    for (int i = lo; i < hi; ++i) {
        const int d = off[i];
        off[i] = running;
        cursor[i] = running;
        running += d;
    }
    if (t == 0) off[N_NODES] = E_EDGES;
}

__global__ __launch_bounds__(256) void k_fill(
    const int* __restrict__ ei, const float* __restrict__ ea,
    int* __restrict__ cursor, int2* __restrict__ csr)
{
    const int e = blockIdx.x * 256 + threadIdx.x;
    if (e >= E_EDGES) return;
    const int dst = ei[E_EDGES + e];
    const int pos = atomicAdd(&cursor[dst], 1);
    csr[pos] = make_int2(ei[e], __float_as_int(ea[e]));
}

// ---------------------------------------------------------------------------
// k_agg: CSR gather over bf16 h rows (256 B/edge vs 512 fp32 -> half the
// bytes AND half the cache lines through the L2/L3 miss path).
// One wave per node; half0 takes [s,mid), half1 [mid,e); 8-deep unroll.
// Lane owns 4 channels (uint2 = 4 bf16). Cross-half combine via shfl_xor(32).
// ---------------------------------------------------------------------------
__global__ __launch_bounds__(256) void k_agg(
    const int* __restrict__ off, const int2* __restrict__ csr,
    const u16* __restrict__ h, const float* __restrict__ ew,
    const float* __restrict__ eb, float* __restrict__ agg)
{
    const int wave = threadIdx.x >> 6;
    const int lane = threadIdx.x & 63;
    const int half = lane >> 5;
    const int c = (lane & 31) * 4;
    const int n = blockIdx.x * 4 + wave;

    const float4 wv = *(const float4*)&ew[c];
    const float4 bv = *(const float4*)&eb[c];

    const int s = off[n], e = off[n + 1];
    const int mid = s + ((e - s + 1) >> 1);
    int i        = half ? mid : s;
    const int hi = half ? e   : mid;

    float ax0 = 0.f, ay0 = 0.f, az0 = 0.f, aw0 = 0.f;
    float ax1 = 0.f, ay1 = 0.f, az1 = 0.f, aw1 = 0.f;

    for (; i + 7 < hi; i += 8) {
        int2 p[8];
        #pragma unroll
        for (int u = 0; u < 8; ++u) p[u] = csr[i + u];
        uint2 hq[8];
        #pragma unroll
        for (int u = 0; u < 8; ++u)
            hq[u] = *(const uint2*)&h[(size_t)p[u].x * H + c];
        #pragma unroll
        for (int u = 0; u < 8; ++u) {
            const float a = __int_as_float(p[u].y);
            const float h0 = bf_lo(hq[u].x), h1 = bf_hi(hq[u].x);
            const float h2 = bf_lo(hq[u].y), h3 = bf_hi(hq[u].y);
            if (u & 1) {
                ax1 += fmaxf(fmaf(a, wv.x, h0) + bv.x, 0.f);
                ay1 += fmaxf(fmaf(a, wv.y, h1) + bv.y, 0.f);
                az1 += fmaxf(fmaf(a, wv.z, h2) + bv.z, 0.f);
                aw1 += fmaxf(fmaf(a, wv.w, h3) + bv.w, 0.f);
            } else {
                ax0 += fmaxf(fmaf(a, wv.x, h0) + bv.x, 0.f);
                ay0 += fmaxf(fmaf(a, wv.y, h1) + bv.y, 0.f);
                az0 += fmaxf(fmaf(a, wv.z, h2) + bv.z, 0.f);
                aw0 += fmaxf(fmaf(a, wv.w, h3) + bv.w, 0.f);
            }
        }
    }
    for (; i < hi; ++i) {
        const int2 p0 = csr[i];
        const uint2 hq = *(const uint2*)&h[(size_t)p0.x * H + c];
        const float a0 = __int_as_float(p0.y);
        ax0 += fmaxf(fmaf(a0, wv.x, bf_lo(hq.x)) + bv.x, 0.f);
        ay0 += fmaxf(fmaf(a0, wv.y, bf_hi(hq.x)) + bv.y, 0.f);
        az0 += fmaxf(fmaf(a0, wv.z, bf_lo(hq.y)) + bv.z, 0.f);
        aw0 += fmaxf(fmaf(a0, wv.w, bf_hi(hq.y)) + bv.w, 0.f);
    }
    ax0 += ax1; ay0 += ay1; az0 += az1; aw0 += aw1;
    ax0 += __shfl_xor(ax0, 32);
    ay0 += __shfl_xor(ay0, 32);
    az0 += __shfl_xor(az0, 32);
    aw0 += __shfl_xor(aw0, 32);
    if (half == 0) {
        float4 r; r.x = ax0; r.y = ay0; r.z = az0; r.w = aw0;
        *(float4*)&agg[(size_t)n * H + c] = r;
    }
}

// ---------------------------------------------------------------------------
// k_gine: node update; h in/out bf16, agg fp32, math fp32.
// ---------------------------------------------------------------------------
#define NPB 8
__global__ __launch_bounds__(256) void k_gine(
    const float* __restrict__ agg, u16* __restrict__ h,
    const float* __restrict__ eps_p,
    const float* __restrict__ w1, const float* __restrict__ b1,
    const float* __restrict__ bn_g, const float* __restrict__ bn_b,
    const float* __restrict__ bn_m, const float* __restrict__ bn_v,
    const float* __restrict__ w2, const float* __restrict__ b2,
    const int first_layer)
{
    const int n0 = blockIdx.x * NPB;
    const int t  = threadIdx.x;
    const int jp = t & 63;  const int j0 = jp * 2;
    const int np = t >> 6;  const int na = np * 2, nb = na + 1;

    __shared__ __align__(16) float s_z[NPB][H];
    __shared__ __align__(16) float s_t[NPB][H];
    __shared__ __align__(16) float s_r[NPB][H];

    const float ep1 = 1.f + eps_p[0];

    for (int i = t; i < NPB * H / 2; i += 256) {   // 512 iters: 2 ch/thread
        const int q = i >> 6, c2 = (i & 63) * 2;
        const int n = n0 + q;
        const u32 hp = *(const u32*)&h[(size_t)n * H + c2];
        const float2 av = *(const float2*)&agg[(size_t)n * H + c2];
        const float h0 = bf_lo(hp), h1 = bf_hi(hp);
        s_r[q][c2] = h0;               s_r[q][c2 + 1] = h1;
        s_z[q][c2] = fmaf(ep1, h0, av.x);
        s_z[q][c2 + 1] = fmaf(ep1, h1, av.y);
    }
    __syncthreads();

    {
        const float2 g = *(const float2*)&bn_g[j0];
        const float2 b = *(const float2*)&bn_b[j0];
        const float2 m = *(const float2*)&bn_m[j0];
        const float2 v = *(const float2*)&bn_v[j0];
        const float2 bb = *(const float2*)&b1[j0];
        const float scx = g.x * rsqrtf(v.x + BN_EPS);
        const float scy = g.y * rsqrtf(v.y + BN_EPS);
        const float shx = fmaf(bb.x - m.x, scx, b.x);
        const float shy = fmaf(bb.y - m.y, scy, b.y);

        float a00 = 0.f, a01 = 0.f, a10 = 0.f, a11 = 0.f;
        for (int k = 0; k < H; k += 4) {
            const float2 w0 = *(const float2*)&w1[(k    ) * H + j0];
            const float2 w1v= *(const float2*)&w1[(k + 1) * H + j0];
            const float2 w2v= *(const float2*)&w1[(k + 2) * H + j0];
            const float2 w3v= *(const float2*)&w1[(k + 3) * H + j0];
            const float4 z0 = *(const float4*)&s_z[na][k];
            const float4 z1 = *(const float4*)&s_z[nb][k];
            a00 = fmaf(z0.x, w0.x,  a00); a01 = fmaf(z0.x, w0.y,  a01);
            a10 = fmaf(z1.x, w0.x,  a10); a11 = fmaf(z1.x, w0.y,  a11);
            a00 = fmaf(z0.y, w1v.x, a00); a01 = fmaf(z0.y, w1v.y, a01);
            a10 = fmaf(z1.y, w1v.x, a10); a11 = fmaf(z1.y, w1v.y, a11);
            a00 = fmaf(z0.z, w2v.x, a00); a01 = fmaf(z0.z, w2v.y, a01);
            a10 = fmaf(z1.z, w2v.x, a10); a11 = fmaf(z1.z, w2v.y, a11);
            a00 = fmaf(z0.w, w3v.x, a00); a01 = fmaf(z0.w, w3v.y, a01);
            a10 = fmaf(z1.w, w3v.x, a10); a11 = fmaf(z1.w, w3v.y, a11);
        }
        s_t[na][j0]     = fmaxf(fmaf(a00, scx, shx), 0.f);
        s_t[na][j0 + 1] = fmaxf(fmaf(a01, scy, shy), 0.f);
        s_t[nb][j0]     = fmaxf(fmaf(a10, scx, shx), 0.f);
        s_t[nb][j0 + 1] = fmaxf(fmaf(a11, scy, shy), 0.f);
    }
    __syncthreads();

    {
        const float2 bb = *(const float2*)&b2[j0];
        float a00 = bb.x, a01 = bb.y, a10 = bb.x, a11 = bb.y;
        for (int k = 0; k < H; k += 4) {
            const float2 w0 = *(const float2*)&w2[(k    ) * H + j0];
            const float2 w1v= *(const float2*)&w2[(k + 1) * H + j0];
            const float2 w2v= *(const float2*)&w2[(k + 2) * H + j0];
            const float2 w3v= *(const float2*)&w2[(k + 3) * H + j0];
            const float4 t0 = *(const float4*)&s_t[na][k];
            const float4 t1 = *(const float4*)&s_t[nb][k];
            a00 = fmaf(t0.x, w0.x,  a00); a01 = fmaf(t0.x, w0.y,  a01);
            a10 = fmaf(t1.x, w0.x,  a10); a11 = fmaf(t1.x, w0.y,  a11);
            a00 = fmaf(t0.y, w1v.x, a00); a01 = fmaf(t0.y, w1v.y, a01);
            a10 = fmaf(t1.y, w1v.x, a10); a11 = fmaf(t1.y, w1v.y, a11);
            a00 = fmaf(t0.z, w2v.x, a00); a01 = fmaf(t0.z, w2v.y, a01);
            a10 = fmaf(t1.z, w2v.x, a10); a11 = fmaf(t1.z, w2v.y, a11);
            a00 = fmaf(t0.w, w3v.x, a00); a01 = fmaf(t0.w, w3v.y, a01);
            a10 = fmaf(t1.w, w3v.x, a10); a11 = fmaf(t1.w, w3v.y, a11);
        }
        float rax, ray, rbx, rby;
        if (first_layer) {
            rax = fmaxf(a00, 0.f); ray = fmaxf(a01, 0.f);
            rbx = fmaxf(a10, 0.f); rby = fmaxf(a11, 0.f);
        } else {
            rax = s_r[na][j0]     + fmaxf(a00, 0.f);
            ray = s_r[na][j0 + 1] + fmaxf(a01, 0.f);
            rbx = s_r[nb][j0]     + fmaxf(a10, 0.f);
            rby = s_r[nb][j0 + 1] + fmaxf(a11, 0.f);
        }
        *(u32*)&h[(size_t)(n0 + na) * H + j0] = pack2bf(rax, ray);
        *(u32*)&h[(size_t)(n0 + nb) * H + j0] = pack2bf(rbx, rby);
    }
}

// ---------------------------------------------------------------------------
// k_out: output head; reads bf16 h.
// ---------------------------------------------------------------------------
__global__ __launch_bounds__(256) void k_out(
    const u16* __restrict__ h, const float* __restrict__ aw,
    const float* __restrict__ ab, float* __restrict__ out)
{
    const int n = blockIdx.x * 2 + (threadIdx.x >> 7);
    const int j = threadIdx.x & 127;
    const int base = (threadIdx.x >> 7) << 7;

    __shared__ float r0[256];
    __shared__ float r1[256];

    union { u32 u; float f; } cv;
    cv.u = (u32)h[(size_t)n * H + j] << 16;
    const float hv = cv.f;
    r0[threadIdx.x] = hv * aw[j * 2 + 0];
    r1[threadIdx.x] = hv * aw[j * 2 + 1];
    __syncthreads();

    for (int s = 64; s > 0; s >>= 1) {
        if (j < s) {
            r0[base + j] += r0[base + j + s];
            r1[base + j] += r1[base + j + s];
        }
        __syncthreads();
    }
    if (j == 0) {
        const float mu = r0[base] + ab[0];
        const float o1 = r1[base] + ab[1];
        const float sp = (o1 > 0.f) ? (o1 + log1pf(expf(-o1)))
                                    : log1pf(expf(o1));
        out[(size_t)n * 2 + 0] = mu;
        out[(size_t)n * 2 + 1] = sp;
    }
}

// ---------------------------------------------------------------------------
extern "C" void kernel_launch(void* const* d_in, const int* in_sizes, int n_in,
                              void* d_out, int out_size, void* d_ws, size_t ws_size,
                              hipStream_t stream)
{
    const float* ensemble = (const float*)d_in[0];
    const float* x        = (const float*)d_in[1];
    const int*   ei       = (const int*)d_in[2];
    const float* ea       = (const float*)d_in[3];
    const float* phi_w1   = (const float*)d_in[4];
    const float* phi_b1   = (const float*)d_in[5];
    const float* phi_w2   = (const float*)d_in[6];
    const float* phi_b2   = (const float*)d_in[7];
    const float* rho_w1   = (const float*)d_in[8];
    const float* rho_b1   = (const float*)d_in[9];
    const float* rho_w2   = (const float*)d_in[10];
    const float* rho_b2   = (const float*)d_in[11];
    const float* dr_w     = (const float*)d_in[12];
    const float* dr_b     = (const float*)d_in[13];
    const float* conv_eps = (const float*)d_in[14];
    const float* edge_w   = (const float*)d_in[15];
    const float* edge_b   = (const float*)d_in[16];
    const float* mlp_w1   = (const float*)d_in[17];
    const float* mlp_b1   = (const float*)d_in[18];
    const float* bn_g     = (const float*)d_in[19];
    const float* bn_b     = (const float*)d_in[20];
    const float* bn_m     = (const float*)d_in[21];
    const float* bn_v     = (const float*)d_in[22];
    const float* mlp_w2   = (const float*)d_in[23];
    const float* mlp_b2   = (const float*)d_in[24];
    const float* aggr_w   = (const float*)d_in[25];
    const float* aggr_b   = (const float*)d_in[26];

    float* out = (float*)d_out;

    // workspace layout (all segment element counts even -> 8B alignment holds)
    float* agg_buf = (float*)d_ws;                          // N*H f32
    float* Wf1     = agg_buf + (size_t)N_NODES * H;         // H*H
    float* bf1     = Wf1 + H * H;                           // H
    float* Wf2     = bf1 + H;                               // H*H
    float* bf2     = Wf2 + H * H;                           // H
    int*   off     = (int*)(bf2 + H);                       // N+2 (padded)
    int*   cursor  = off + (N_NODES + 2);                   // N
    int2*  csr     = (int2*)(cursor + N_NODES);             // E (8B aligned)
    u16*   h_bf    = (u16*)(csr + E_EDGES);                 // N*H bf16

    const int eblocks = (E_EDGES + 255) / 256;

    // fold weights, then embed
    k_fold<<<256, 256, 0, stream>>>(phi_w2, phi_b2, rho_w1, rho_b1,
                                    rho_w2, rho_b2, dr_w, dr_b,
                                    Wf1, bf1, Wf2, bf2);
    k_embed<<<N_NODES / ENB, 256, 0, stream>>>(
        ensemble, x, phi_w1, phi_b1, Wf1, bf1, Wf2, bf2, dr_w, h_bf);

    // CSR build (once)
    hipMemsetAsync(off, 0, (N_NODES + 1) * sizeof(int), stream);
    k_count<<<eblocks, 256, 0, stream>>>(ei, off);
    k_scan<<<1, 1024, 0, stream>>>(off, cursor);
    k_fill<<<eblocks, 256, 0, stream>>>(ei, ea, cursor, csr);

    // GINE layers
    for (int i = 0; i < L_LAYERS; ++i) {
        k_agg<<<N_NODES / 4, 256, 0, stream>>>(
            off, csr, h_bf,
            edge_w + (size_t)i * H, edge_b + (size_t)i * H, agg_buf);
        k_gine<<<N_NODES / NPB, 256, 0, stream>>>(
            agg_buf, h_bf, conv_eps + i,
            mlp_w1 + (size_t)i * H * H, mlp_b1 + (size_t)i * H,
            bn_g + (size_t)i * H, bn_b + (size_t)i * H,
            bn_m + (size_t)i * H, bn_v + (size_t)i * H,
            mlp_w2 + (size_t)i * H * H, mlp_b2 + (size_t)i * H,
            (i == 0) ? 1 : 0);
    }

    k_out<<<N_NODES / 2, 256, 0, stream>>>(h_bf, aggr_w, aggr_b, out);
}

// Round 8
// 1323.174 us; speedup vs baseline: 1.1396x; 1.0641x over previous
//
#include <hip/hip_runtime.h>
#include <math.h>

#define N_NODES 50000
#define M_ENS   20
#define C_IN    32
#define H       128
#define E_EDGES 800000
#define L_LAYERS 3
#define BN_EPS  1e-5f

typedef unsigned short u16;
typedef unsigned int   u32;

// bf16 helpers (RNE pack, cheap unpack)
__device__ __forceinline__ float bf_lo(u32 p) {
    union { u32 u; float f; } v; v.u = p << 16; return v.f;
}
__device__ __forceinline__ float bf_hi(u32 p) {
    union { u32 u; float f; } v; v.u = p & 0xFFFF0000u; return v.f;
}
__device__ __forceinline__ u16 f2bf(float f) {
    union { float f; u32 u; } v; v.f = f;
    const u32 r = v.u + 0x7FFFu + ((v.u >> 16) & 1u);
    return (u16)(r >> 16);
}
__device__ __forceinline__ u32 pack2bf(float a, float b) {
    return (u32)f2bf(a) | ((u32)f2bf(b) << 16);
}

// ---------------------------------------------------------------------------
// k_fold: precompute folded weights (unchanged).
// ---------------------------------------------------------------------------
__global__ __launch_bounds__(256) void k_fold(
    const float* __restrict__ w2,  const float* __restrict__ b2,
    const float* __restrict__ rw1, const float* __restrict__ rb1,
    const float* __restrict__ rw2, const float* __restrict__ rb2,
    const float* __restrict__ dr_w, const float* __restrict__ dr_b,
    float* __restrict__ Wf1, float* __restrict__ bf1,
    float* __restrict__ Wf2, float* __restrict__ bf2)
{
    const int g = blockIdx.x >> 7;
    const int j = blockIdx.x & 127;
    const int t = threadIdx.x;

    const float* A  = g ? rw2 : w2;
    const float* Bm = g ? (dr_w + C_IN * H) : rw1;

    __shared__ float s_col[H];
    if (t < H) s_col[t] = Bm[t * H + j];
    __syncthreads();

    const int r = t >> 1, q = t & 1;
    const float* arow = &A[r * H + q * 64];
    const float* cp = &s_col[q * 64];
    float acc = 0.f;
    #pragma unroll
    for (int u = 0; u < 64; u += 4) {
        const float4 av = *(const float4*)&arow[u];
        acc = fmaf(av.x, cp[u], acc);
        acc = fmaf(av.y, cp[u + 1], acc);
        acc = fmaf(av.z, cp[u + 2], acc);
        acc = fmaf(av.w, cp[u + 3], acc);
    }
    acc += __shfl_xor(acc, 1);
    if (q == 0) (g ? Wf2 : Wf1)[r * H + j] = acc;

    if (t == 0) {
        float bacc = g ? dr_b[j] : rb1[j];
        const float* bsrc = g ? rb2 : b2;
        const float scale = g ? 1.f : 20.f;
        for (int k = 0; k < H; ++k)
            bacc = fmaf(scale * bsrc[k], s_col[k], bacc);
        (g ? bf2 : bf1)[j] = bacc;
    }
}

// ---------------------------------------------------------------------------
// k_embed: R7 structure (best measured). bf16 h store.
// ---------------------------------------------------------------------------
#define ENB 8
__global__ __launch_bounds__(256) void k_embed(
    const float* __restrict__ ensemble, const float* __restrict__ x,
    const float* __restrict__ phi_w1,   const float* __restrict__ phi_b1,
    const float* __restrict__ Wf1, const float* __restrict__ bf1,
    const float* __restrict__ Wf2, const float* __restrict__ bf2,
    const float* __restrict__ dr_w,
    u16* __restrict__ h_out)
{
    const int n0 = blockIdx.x * ENB;
    const int t  = threadIdx.x;
    const int jp = t & 63;  const int j0 = jp * 2;
    const int np = t >> 6;  const int na = np * 2, nb = na + 1;

    __shared__ __align__(16) float s_ens[ENB * M_ENS * C_IN];
    __shared__ __align__(16) float s_h[ENB][H];
    __shared__ __align__(16) float s_t[ENB][H];
    __shared__ __align__(16) float s_x[ENB][C_IN];

    for (int i = t; i < ENB * M_ENS * C_IN; i += 256)
        s_ens[i] = ensemble[(size_t)n0 * (M_ENS * C_IN) + i];
    s_x[t >> 5][t & 31] = x[(size_t)n0 * C_IN + t];
    __syncthreads();

    float w1a[C_IN], w1b[C_IN];
    #pragma unroll
    for (int k = 0; k < C_IN; ++k) {
        w1a[k] = phi_w1[k * H + j0];
        w1b[k] = phi_w1[k * H + j0 + 1];
    }
    const float b1a = phi_b1[j0], b1b = phi_b1[j0 + 1];

    float hs00 = 0.f, hs01 = 0.f, hs10 = 0.f, hs11 = 0.f;
    for (int m = 0; m < M_ENS; ++m) {
        float a00 = b1a, a01 = b1b, a10 = b1a, a11 = b1b;
        const float* ea = &s_ens[(na * M_ENS + m) * C_IN];
        const float* eb = &s_ens[(nb * M_ENS + m) * C_IN];
        #pragma unroll
        for (int k = 0; k < C_IN; k += 4) {
            const float4 e0 = *(const float4*)&ea[k];
            const float4 e1 = *(const float4*)&eb[k];
            a00 = fmaf(e0.x, w1a[k],   a00); a01 = fmaf(e0.x, w1b[k],   a01);
            a10 = fmaf(e1.x, w1a[k],   a10); a11 = fmaf(e1.x, w1b[k],   a11);
            a00 = fmaf(e0.y, w1a[k+1], a00); a01 = fmaf(e0.y, w1b[k+1], a01);
            a10 = fmaf(e1.y, w1a[k+1], a10); a11 = fmaf(e1.y, w1b[k+1], a11);
            a00 = fmaf(e0.z, w1a[k+2], a00); a01 = fmaf(e0.z, w1b[k+2], a01);
            a10 = fmaf(e1.z, w1a[k+2], a10); a11 = fmaf(e1.z, w1b[k+2], a11);
            a00 = fmaf(e0.w, w1a[k+3], a00); a01 = fmaf(e0.w, w1b[k+3], a01);
            a10 = fmaf(e1.w, w1a[k+3], a10); a11 = fmaf(e1.w, w1b[k+3], a11);
        }
        hs00 += fmaxf(a00, 0.f); hs01 += fmaxf(a01, 0.f);
        hs10 += fmaxf(a10, 0.f); hs11 += fmaxf(a11, 0.f);
    }
    s_h[na][j0] = hs00; s_h[na][j0 + 1] = hs01;
    s_h[nb][j0] = hs10; s_h[nb][j0 + 1] = hs11;
    __syncthreads();

    {
        const float2 bf = *(const float2*)&bf1[j0];
        float a00 = bf.x, a01 = bf.y, a10 = bf.x, a11 = bf.y;
        for (int k = 0; k < H; k += 4) {
            const float2 w0 = *(const float2*)&Wf1[(k    ) * H + j0];
            const float2 w1v= *(const float2*)&Wf1[(k + 1) * H + j0];
            const float2 w2v= *(const float2*)&Wf1[(k + 2) * H + j0];
            const float2 w3v= *(const float2*)&Wf1[(k + 3) * H + j0];
            const float4 h0 = *(const float4*)&s_h[na][k];
            const float4 h1 = *(const float4*)&s_h[nb][k];
            a00 = fmaf(h0.x, w0.x,  a00); a01 = fmaf(h0.x, w0.y,  a01);
            a10 = fmaf(h1.x, w0.x,  a10); a11 = fmaf(h1.x, w0.y,  a11);
            a00 = fmaf(h0.y, w1v.x, a00); a01 = fmaf(h0.y, w1v.y, a01);
            a10 = fmaf(h1.y, w1v.x, a10); a11 = fmaf(h1.y, w1v.y, a11);
            a00 = fmaf(h0.z, w2v.x, a00); a01 = fmaf(h0.z, w2v.y, a01);
            a10 = fmaf(h1.z, w2v.x, a10); a11 = fmaf(h1.z, w2v.y, a11);
            a00 = fmaf(h0.w, w3v.x, a00); a01 = fmaf(h0.w, w3v.y, a01);
            a10 = fmaf(h1.w, w3v.x, a10); a11 = fmaf(h1.w, w3v.y, a11);
        }
        s_t[na][j0] = fmaxf(a00, 0.f); s_t[na][j0 + 1] = fmaxf(a01, 0.f);
        s_t[nb][j0] = fmaxf(a10, 0.f); s_t[nb][j0 + 1] = fmaxf(a11, 0.f);
    }
    __syncthreads();

    {
        const float2 bf = *(const float2*)&bf2[j0];
        float a00 = bf.x, a01 = bf.y, a10 = bf.x, a11 = bf.y;
        for (int k = 0; k < H; k += 4) {
            const float2 w0 = *(const float2*)&Wf2[(k    ) * H + j0];
            const float2 w1v= *(const float2*)&Wf2[(k + 1) * H + j0];
            const float2 w2v= *(const float2*)&Wf2[(k + 2) * H + j0];
            const float2 w3v= *(const float2*)&Wf2[(k + 3) * H + j0];
            const float4 t0 = *(const float4*)&s_t[na][k];
            const float4 t1 = *(const float4*)&s_t[nb][k];
            a00 = fmaf(t0.x, w0.x,  a00); a01 = fmaf(t0.x, w0.y,  a01);
            a10 = fmaf(t1.x, w0.x,  a10); a11 = fmaf(t1.x, w0.y,  a11);
            a00 = fmaf(t0.y, w1v.x, a00); a01 = fmaf(t0.y, w1v.y, a01);
            a10 = fmaf(t1.y, w1v.x, a10); a11 = fmaf(t1.y, w1v.y, a11);
            a00 = fmaf(t0.z, w2v.x, a00); a01 = fmaf(t0.z, w2v.y, a01);
            a10 = fmaf(t1.z, w2v.x, a10); a11 = fmaf(t1.z, w2v.y, a11);
            a00 = fmaf(t0.w, w3v.x, a00); a01 = fmaf(t0.w, w3v.y, a01);
            a10 = fmaf(t1.w, w3v.x, a10); a11 = fmaf(t1.w, w3v.y, a11);
        }
        #pragma unroll
        for (int k = 0; k < C_IN; k += 4) {
            const float2 w0 = *(const float2*)&dr_w[(k    ) * H + j0];
            const float2 w1v= *(const float2*)&dr_w[(k + 1) * H + j0];
            const float2 w2v= *(const float2*)&dr_w[(k + 2) * H + j0];
            const float2 w3v= *(const float2*)&dr_w[(k + 3) * H + j0];
            const float4 x0 = *(const float4*)&s_x[na][k];
            const float4 x1 = *(const float4*)&s_x[nb][k];
            a00 = fmaf(x0.x, w0.x,  a00); a01 = fmaf(x0.x, w0.y,  a01);
            a10 = fmaf(x1.x, w0.x,  a10); a11 = fmaf(x1.x, w0.y,  a11);
            a00 = fmaf(x0.y, w1v.x, a00); a01 = fmaf(x0.y, w1v.y, a01);
            a10 = fmaf(x1.y, w1v.x, a10); a11 = fmaf(x1.y, w1v.y, a11);
            a00 = fmaf(x0.z, w2v.x, a00); a01 = fmaf(x0.z, w2v.y, a01);
            a10 = fmaf(x1.z, w2v.x, a10); a11 = fmaf(x1.z, w2v.y, a11);
            a00 = fmaf(x0.w, w3v.x, a00); a01 = fmaf(x0.w, w3v.y, a01);
            a10 = fmaf(x1.w, w3v.x, a10); a11 = fmaf(x1.w, w3v.y, a11);
        }
        *(u32*)&h_out[(size_t)(n0 + na) * H + j0] = pack2bf(a00, a01);
        *(u32*)&h_out[(size_t)(n0 + nb) * H + j0] = pack2bf(a10, a11);
    }
}

// ---------------------------------------------------------------------------
// CSR build (unchanged).
// ---------------------------------------------------------------------------
__global__ __launch_bounds__(256) void k_count(
    const int* __restrict__ ei, int* __restrict__ deg)
{
    const int e = blockIdx.x * 256 + threadIdx.x;
    if (e >= E_EDGES) return;
    atomicAdd(&deg[ei[E_EDGES + e]], 1);
}

__global__ __launch_bounds__(1024) void k_scan(
    int* __restrict__ off, int* __restrict__ cursor)
{
    const int t = threadIdx.x;
    const int CHUNK = (N_NODES + 1023) / 1024;
    const int lo = t * CHUNK;
    const int hi = min(lo + CHUNK, N_NODES);

    int mysum = 0;
    for (int i = lo; i < hi; ++i) mysum += off[i];

    __shared__ int s[1024];
    s[t] = mysum;
    __syncthreads();
    for (int d = 1; d < 1024; d <<= 1) {
        int v = (t >= d) ? s[t - d] : 0;
        __syncthreads();
        s[t] += v;
        __syncthreads();
    }
    int running = s[t] - mysum;

    for (int i = lo; i < hi; ++i) {
        const int d = off[i];
        off[i] = running;
        cursor[i] = running;
        running += d;
    }
    if (t == 0) off[N_NODES] = E_EDGES;
}

__global__ __launch_bounds__(256) void k_fill(
    const int* __restrict__ ei, const float* __restrict__ ea,
    int* __restrict__ cursor, int2* __restrict__ csr)
{
    const int e = blockIdx.x * 256 + threadIdx.x;
    if (e >= E_EDGES) return;
    const int dst = ei[E_EDGES + e];
    const int pos = atomicAdd(&cursor[dst], 1);
    csr[pos] = make_int2(ei[e], __float_as_int(ea[e]));
}

// ---------------------------------------------------------------------------
// k_layer: FUSED gather + GINE node update (+ output head on last layer).
//   agg[n] = sum_e relu(h_in[src] + a*ew + eb)   (CSR gather, bf16 rows)
//   z = (1+eps)*h_in[n] + agg; t = relu(BN(z@w1+b1)); cvec = t@w2+b2
//   h_out[n] = relu(cvec) (layer0) / h_in[n] + relu(cvec)
//   last layer: out = head(h) computed in-register, h_out not written.
// 8 nodes per 256-thread block. Gather: wave np handles nodes 2np,2np+1 —
// half-wave per node, lane owns 4 channels (uint2 of bf16). Double-buffered
// h (read h_in, write h_out) keeps cross-block gather/update race-free.
// ---------------------------------------------------------------------------
#define NPB 8
__global__ __launch_bounds__(256) void k_layer(
    const int* __restrict__ off, const int2* __restrict__ csr,
    const u16* __restrict__ h_in, u16* __restrict__ h_out,
    const float* __restrict__ ew, const float* __restrict__ eb,
    const float* __restrict__ eps_p,
    const float* __restrict__ w1, const float* __restrict__ b1,
    const float* __restrict__ bn_g, const float* __restrict__ bn_b,
    const float* __restrict__ bn_m, const float* __restrict__ bn_v,
    const float* __restrict__ w2, const float* __restrict__ b2,
    const int first_layer, const int last_layer,
    const float* __restrict__ aw, const float* __restrict__ ab,
    float* __restrict__ out)
{
    const int n0 = blockIdx.x * NPB;
    const int t  = threadIdx.x;
    const int jp = t & 63;  const int j0 = jp * 2;
    const int np = t >> 6;  const int na = np * 2, nb = na + 1;

    __shared__ __align__(16) float s_z[NPB][H];
    __shared__ __align__(16) float s_t[NPB][H];
    __shared__ __align__(16) float s_r[NPB][H];

    const float ep1 = 1.f + eps_p[0];

    // ---- phase 1: gather. half-wave h owns node n0 + 2*np + h ----
    {
        const int lane = t & 63;
        const int half = lane >> 5;
        const int c = (lane & 31) * 4;
        const int q = na + half;            // node slot within block
        const int n = n0 + q;

        const float4 wv = *(const float4*)&ew[c];
        const float4 bv = *(const float4*)&eb[c];

        int i        = off[n];
        const int hi = off[n + 1];

        float ax0 = 0.f, ay0 = 0.f, az0 = 0.f, aw0 = 0.f;
        float ax1 = 0.f, ay1 = 0.f, az1 = 0.f, aw1 = 0.f;

        for (; i + 7 < hi; i += 8) {
            int2 p[8];
            #pragma unroll
            for (int u = 0; u < 8; ++u) p[u] = csr[i + u];
            uint2 hq[8];
            #pragma unroll
            for (int u = 0; u < 8; ++u)
                hq[u] = *(const uint2*)&h_in[(size_t)p[u].x * H + c];
            #pragma unroll
            for (int u = 0; u < 8; ++u) {
                const float a = __int_as_float(p[u].y);
                const float h0 = bf_lo(hq[u].x), h1 = bf_hi(hq[u].x);
                const float h2 = bf_lo(hq[u].y), h3 = bf_hi(hq[u].y);
                if (u & 1) {
                    ax1 += fmaxf(fmaf(a, wv.x, h0) + bv.x, 0.f);
                    ay1 += fmaxf(fmaf(a, wv.y, h1) + bv.y, 0.f);
                    az1 += fmaxf(fmaf(a, wv.z, h2) + bv.z, 0.f);
                    aw1 += fmaxf(fmaf(a, wv.w, h3) + bv.w, 0.f);
                } else {
                    ax0 += fmaxf(fmaf(a, wv.x, h0) + bv.x, 0.f);
                    ay0 += fmaxf(fmaf(a, wv.y, h1) + bv.y, 0.f);
                    az0 += fmaxf(fmaf(a, wv.z, h2) + bv.z, 0.f);
                    aw0 += fmaxf(fmaf(a, wv.w, h3) + bv.w, 0.f);
                }
            }
        }
        for (; i < hi; ++i) {
            const int2 p0 = csr[i];
            const uint2 hq = *(const uint2*)&h_in[(size_t)p0.x * H + c];
            const float a0 = __int_as_float(p0.y);
            ax0 += fmaxf(fmaf(a0, wv.x, bf_lo(hq.x)) + bv.x, 0.f);
            ay0 += fmaxf(fmaf(a0, wv.y, bf_hi(hq.x)) + bv.y, 0.f);
            az0 += fmaxf(fmaf(a0, wv.z, bf_lo(hq.y)) + bv.z, 0.f);
            aw0 += fmaxf(fmaf(a0, wv.w, bf_hi(hq.y)) + bv.w, 0.f);
        }
        ax0 += ax1; ay0 += ay1; az0 += az1; aw0 += aw1;

        // own-node h row (coalesced 256B per half) -> z, r
        const uint2 ho = *(const uint2*)&h_in[(size_t)n * H + c];
        const float r0 = bf_lo(ho.x), r1 = bf_hi(ho.x);
        const float r2 = bf_lo(ho.y), r3 = bf_hi(ho.y);
        *(float4*)&s_r[q][c] = make_float4(r0, r1, r2, r3);
        *(float4*)&s_z[q][c] = make_float4(
            fmaf(ep1, r0, ax0), fmaf(ep1, r1, ay0),
            fmaf(ep1, r2, az0), fmaf(ep1, r3, aw0));
    }
    __syncthreads();

    // ---- phase 2: matmul1 + BN + relu ----
    {
        const float2 g = *(const float2*)&bn_g[j0];
        const float2 b = *(const float2*)&bn_b[j0];
        const float2 m = *(const float2*)&bn_m[j0];
        const float2 v = *(const float2*)&bn_v[j0];
        const float2 bb = *(const float2*)&b1[j0];
        const float scx = g.x * rsqrtf(v.x + BN_EPS);
        const float scy = g.y * rsqrtf(v.y + BN_EPS);
        const float shx = fmaf(bb.x - m.x, scx, b.x);
        const float shy = fmaf(bb.y - m.y, scy, b.y);

        float a00 = 0.f, a01 = 0.f, a10 = 0.f, a11 = 0.f;
        for (int k = 0; k < H; k += 4) {
            const float2 w0 = *(const float2*)&w1[(k    ) * H + j0];
            const float2 w1v= *(const float2*)&w1[(k + 1) * H + j0];
            const float2 w2v= *(const float2*)&w1[(k + 2) * H + j0];
            const float2 w3v= *(const float2*)&w1[(k + 3) * H + j0];
            const float4 z0 = *(const float4*)&s_z[na][k];
            const float4 z1 = *(const float4*)&s_z[nb][k];
            a00 = fmaf(z0.x, w0.x,  a00); a01 = fmaf(z0.x, w0.y,  a01);
            a10 = fmaf(z1.x, w0.x,  a10); a11 = fmaf(z1.x, w0.y,  a11);
            a00 = fmaf(z0.y, w1v.x, a00); a01 = fmaf(z0.y, w1v.y, a01);
            a10 = fmaf(z1.y, w1v.x, a10); a11 = fmaf(z1.y, w1v.y, a11);
            a00 = fmaf(z0.z, w2v.x, a00); a01 = fmaf(z0.z, w2v.y, a01);
            a10 = fmaf(z1.z, w2v.x, a10); a11 = fmaf(z1.z, w2v.y, a11);
            a00 = fmaf(z0.w, w3v.x, a00); a01 = fmaf(z0.w, w3v.y, a01);
            a10 = fmaf(z1.w, w3v.x, a10); a11 = fmaf(z1.w, w3v.y, a11);
        }
        s_t[na][j0]     = fmaxf(fmaf(a00, scx, shx), 0.f);
        s_t[na][j0 + 1] = fmaxf(fmaf(a01, scy, shy), 0.f);
        s_t[nb][j0]     = fmaxf(fmaf(a10, scx, shx), 0.f);
        s_t[nb][j0 + 1] = fmaxf(fmaf(a11, scy, shy), 0.f);
    }
    __syncthreads();

    // ---- phase 3: matmul2 + relu + residual (+ head on last layer) ----
    {
        const float2 bb = *(const float2*)&b2[j0];
        float a00 = bb.x, a01 = bb.y, a10 = bb.x, a11 = bb.y;
        for (int k = 0; k < H; k += 4) {
            const float2 w0 = *(const float2*)&w2[(k    ) * H + j0];
            const float2 w1v= *(const float2*)&w2[(k + 1) * H + j0];
            const float2 w2v= *(const float2*)&w2[(k + 2) * H + j0];
            const float2 w3v= *(const float2*)&w2[(k + 3) * H + j0];
            const float4 t0 = *(const float4*)&s_t[na][k];
            const float4 t1 = *(const float4*)&s_t[nb][k];
            a00 = fmaf(t0.x, w0.x,  a00); a01 = fmaf(t0.x, w0.y,  a01);
            a10 = fmaf(t1.x, w0.x,  a10); a11 = fmaf(t1.x, w0.y,  a11);
            a00 = fmaf(t0.y, w1v.x, a00); a01 = fmaf(t0.y, w1v.y, a01);
            a10 = fmaf(t1.y, w1v.x, a10); a11 = fmaf(t1.y, w1v.y, a11);
            a00 = fmaf(t0.z, w2v.x, a00); a01 = fmaf(t0.z, w2v.y, a01);
            a10 = fmaf(t1.z, w2v.x, a10); a11 = fmaf(t1.z, w2v.y, a11);
            a00 = fmaf(t0.w, w3v.x, a00); a01 = fmaf(t0.w, w3v.y, a01);
            a10 = fmaf(t1.w, w3v.x, a10); a11 = fmaf(t1.w, w3v.y, a11);
        }
        float rax, ray, rbx, rby;
        if (first_layer) {
            rax = fmaxf(a00, 0.f); ray = fmaxf(a01, 0.f);
            rbx = fmaxf(a10, 0.f); rby = fmaxf(a11, 0.f);
        } else {
            rax = s_r[na][j0]     + fmaxf(a00, 0.f);
            ray = s_r[na][j0 + 1] + fmaxf(a01, 0.f);
            rbx = s_r[nb][j0]     + fmaxf(a10, 0.f);
            rby = s_r[nb][j0 + 1] + fmaxf(a11, 0.f);
        }
        if (!last_layer) {
            *(u32*)&h_out[(size_t)(n0 + na) * H + j0] = pack2bf(rax, ray);
            *(u32*)&h_out[(size_t)(n0 + nb) * H + j0] = pack2bf(rbx, rby);
        } else {
            // head: out = h @ aw + ab; mu, softplus(sigma). Wave = np group;
            // 64 lanes hold channels j0,j0+1 of nodes na,nb -> shfl reduce.
            const float2 awx = *(const float2*)&aw[j0 * 2];          // ch j0
            const float2 awy = *(const float2*)&aw[(j0 + 1) * 2];    // ch j0+1
            float mu_a = rax * awx.x + ray * awy.x;
            float sg_a = rax * awx.y + ray * awy.y;
            float mu_b = rbx * awx.x + rby * awy.x;
            float sg_b = rbx * awx.y + rby * awy.y;
            #pragma unroll
            for (int sft = 32; sft > 0; sft >>= 1) {
                mu_a += __shfl_down(mu_a, sft);
                sg_a += __shfl_down(sg_a, sft);
                mu_b += __shfl_down(mu_b, sft);
                sg_b += __shfl_down(sg_b, sft);
            }
            if (jp == 0) {
                const float o1a = sg_a + ab[1];
                const float o1b = sg_b + ab[1];
                const float spa = (o1a > 0.f) ? (o1a + log1pf(expf(-o1a)))
                                              : log1pf(expf(o1a));
                const float spb = (o1b > 0.f) ? (o1b + log1pf(expf(-o1b)))
                                              : log1pf(expf(o1b));
                out[(size_t)(n0 + na) * 2 + 0] = mu_a + ab[0];
                out[(size_t)(n0 + na) * 2 + 1] = spa;
                out[(size_t)(n0 + nb) * 2 + 0] = mu_b + ab[0];
                out[(size_t)(n0 + nb) * 2 + 1] = spb;
            }
        }
    }
}

// ---------------------------------------------------------------------------
extern "C" void kernel_launch(void* const* d_in, const int* in_sizes, int n_in,
                              void* d_out, int out_size, void* d_ws, size_t ws_size,
                              hipStream_t stream)
{
    const float* ensemble = (const float*)d_in[0];
    const float* x        = (const float*)d_in[1];
    const int*   ei       = (const int*)d_in[2];
    const float* ea       = (const float*)d_in[3];
    const float* phi_w1   = (const float*)d_in[4];
    const float* phi_b1   = (const float*)d_in[5];
    const float* phi_w2   = (const float*)d_in[6];
    const float* phi_b2   = (const float*)d_in[7];
    const float* rho_w1   = (const float*)d_in[8];
    const float* rho_b1   = (const float*)d_in[9];
    const float* rho_w2   = (const float*)d_in[10];
    const float* rho_b2   = (const float*)d_in[11];
    const float* dr_w     = (const float*)d_in[12];
    const float* dr_b     = (const float*)d_in[13];
    const float* conv_eps = (const float*)d_in[14];
    const float* edge_w   = (const float*)d_in[15];
    const float* edge_b   = (const float*)d_in[16];
    const float* mlp_w1   = (const float*)d_in[17];
    const float* mlp_b1   = (const float*)d_in[18];
    const float* bn_g     = (const float*)d_in[19];
    const float* bn_b     = (const float*)d_in[20];
    const float* bn_m     = (const float*)d_in[21];
    const float* bn_v     = (const float*)d_in[22];
    const float* mlp_w2   = (const float*)d_in[23];
    const float* mlp_b2   = (const float*)d_in[24];
    const float* aggr_w   = (const float*)d_in[25];
    const float* aggr_b   = (const float*)d_in[26];

    float* out = (float*)d_out;

    // workspace layout
    float* Wf1     = (float*)d_ws;                          // H*H
    float* bf1     = Wf1 + H * H;                           // H
    float* Wf2     = bf1 + H;                               // H*H
    float* bf2     = Wf2 + H * H;                           // H
    int*   off     = (int*)(bf2 + H);                       // N+2 (padded)
    int*   cursor  = off + (N_NODES + 2);                   // N
    int2*  csr     = (int2*)(cursor + N_NODES);             // E (8B aligned)
    u16*   h_a     = (u16*)(csr + E_EDGES);                 // N*H bf16
    u16*   h_b     = h_a + (size_t)N_NODES * H;             // N*H bf16

    const int eblocks = (E_EDGES + 255) / 256;

    // fold weights, then embed -> h_a
    k_fold<<<256, 256, 0, stream>>>(phi_w2, phi_b2, rho_w1, rho_b1,
                                    rho_w2, rho_b2, dr_w, dr_b,
                                    Wf1, bf1, Wf2, bf2);
    k_embed<<<N_NODES / ENB, 256, 0, stream>>>(
        ensemble, x, phi_w1, phi_b1, Wf1, bf1, Wf2, bf2, dr_w, h_a);

    // CSR build (once)
    hipMemsetAsync(off, 0, (N_NODES + 1) * sizeof(int), stream);
    k_count<<<eblocks, 256, 0, stream>>>(ei, off);
    k_scan<<<1, 1024, 0, stream>>>(off, cursor);
    k_fill<<<eblocks, 256, 0, stream>>>(ei, ea, cursor, csr);

    // fused GINE layers (double-buffered h; last layer writes head to out)
    u16* hin = h_a; u16* hout = h_b;
    for (int i = 0; i < L_LAYERS; ++i) {
        k_layer<<<N_NODES / NPB, 256, 0, stream>>>(
            off, csr, hin, hout,
            edge_w + (size_t)i * H, edge_b + (size_t)i * H, conv_eps + i,
            mlp_w1 + (size_t)i * H * H, mlp_b1 + (size_t)i * H,
            bn_g + (size_t)i * H, bn_b + (size_t)i * H,
            bn_m + (size_t)i * H, bn_v + (size_t)i * H,
            mlp_w2 + (size_t)i * H * H, mlp_b2 + (size_t)i * H,
            (i == 0) ? 1 : 0, (i == L_LAYERS - 1) ? 1 : 0,
            aggr_w, aggr_b, out);
        u16* tmp = hin; hin = hout; hout = tmp;
    }
}